// Round 6
// baseline (79.829 us; speedup 1.0000x reference)
//
#include <hip/hip_runtime.h>
#include <math.h>

typedef short bf16x8 __attribute__((ext_vector_type(8)));
typedef float f32x4 __attribute__((ext_vector_type(4)));
typedef unsigned short u16;
typedef unsigned int u32;

// ws byte offsets: QT (B,N,32) bf16, KT (B,N,32) bf16,
// VW (B,32,1032) bf16 (1024 + 8 pad per kd row, pad zeroed by proj),
// QXY (B,N,2) f32, KXY (B,N,2) f32
#define WS_QT  0
#define WS_KT  1048576
#define WS_VW  2097152
#define WS_QXY 3153920
#define WS_KXY 3284992
#define VWS    1032

__device__ __forceinline__ u16 f2bf(float f) {
    u32 u = __float_as_uint(f);
    u += 0x7fffu + ((u >> 16) & 1u);
    return (u16)(u >> 16);
}
__device__ __forceinline__ u32 pk2(float a, float b) {
    return (u32)f2bf(a) | ((u32)f2bf(b) << 16);
}

// ---------- projections: 1024 blocks = (class, 64-pos chunk) ----------
// class 0=Q, 1=K, 2=V, 3=XY. Per block: 32 (or 4) j-rows x 64 positions.
// 4 blocks/CU (grid), 16 waves/CU -> LDS broadcast-read latency hidden.
// Per-j FMA order identical to round 5 -> bit-identical outputs.
__global__ __launch_bounds__(256, 4) void proj_kernel(
    const float* __restrict__ x,
    const float* __restrict__ Wq, const float* __restrict__ Wk,
    const float* __restrict__ Wv, const float* __restrict__ Wqxy,
    const float* __restrict__ Wkxy, char* __restrict__ wsb)
{
    u16* QT = (u16*)(wsb + WS_QT);
    u16* KT = (u16*)(wsb + WS_KT);
    u16* VW = (u16*)(wsb + WS_VW);
    float* QXY = (float*)(wsb + WS_QXY);
    float* KXY = (float*)(wsb + WS_KXY);

    __shared__ float w_lds[32 * 64];     // 8 KB
    __shared__ float o_lds[64 * 33];     // 8.4 KB, stride 33

    int tid = threadIdx.x;
    int cls = blockIdx.x & 3;
    int chunk = blockIdx.x >> 2;         // 0..255
    int b = chunk >> 4, n0 = (chunk & 15) << 6;
    int lane = tid & 63, jg = tid >> 6;
    int n = n0 + lane;

    // stage this class's weights as float4
    if (cls == 0) {
        for (int i = tid; i < 512; i += 256)
            ((float4*)w_lds)[i] = ((const float4*)Wq)[i];
    } else if (cls == 1) {
        for (int i = tid; i < 512; i += 256)
            ((float4*)w_lds)[i] = ((const float4*)Wk)[i];
    } else if (cls == 2) {
        for (int i = tid; i < 512; i += 256)
            ((float4*)w_lds)[i] = ((const float4*)Wv)[i];
    } else {
        if (tid < 64)
            ((float4*)w_lds)[tid] = (tid < 32) ? ((const float4*)Wqxy)[tid]
                                               : ((const float4*)Wkxy)[tid - 32];
    }

    float xr[64];
    #pragma unroll
    for (int c = 0; c < 64; c++) xr[c] = x[(((b << 6) + c) << 10) + n];

    __syncthreads();

    if (cls < 3) {
        #pragma unroll
        for (int jj = 0; jj < 8; jj++) {
            int j = (jg << 3) + jj;
            const float4* wr = (const float4*)&w_lds[j << 6];
            float a0 = 0.f, a1 = 0.f, a2 = 0.f, a3 = 0.f;
            #pragma unroll
            for (int c4 = 0; c4 < 16; c4++) {
                float4 w4 = wr[c4];
                a0 += w4.x * xr[c4 * 4];
                a1 += w4.y * xr[c4 * 4 + 1];
                a2 += w4.z * xr[c4 * 4 + 2];
                a3 += w4.w * xr[c4 * 4 + 3];
            }
            o_lds[lane * 33 + j] = (a0 + a1) + (a2 + a3);
        }
    } else {
        const float4* wr = (const float4*)&w_lds[jg << 6];
        float a0 = 0.f, a1 = 0.f, a2 = 0.f, a3 = 0.f;
        #pragma unroll
        for (int c4 = 0; c4 < 16; c4++) {
            float4 w4 = wr[c4];
            a0 += w4.x * xr[c4 * 4];
            a1 += w4.y * xr[c4 * 4 + 1];
            a2 += w4.z * xr[c4 * 4 + 2];
            a3 += w4.w * xr[c4 * 4 + 3];
        }
        o_lds[lane * 33 + jg] = (a0 + a1) + (a2 + a3);
    }
    __syncthreads();

    if (cls == 0) {
        int p = tid >> 2, qr = tid & 3;
        const float* src = &o_lds[p * 33 + (qr << 3)];
        uint4 d;
        d.x = pk2(src[0], src[1]); d.y = pk2(src[2], src[3]);
        d.z = pk2(src[4], src[5]); d.w = pk2(src[6], src[7]);
        *(uint4*)&QT[(((b << 10) + n0 + p) << 5) + (qr << 3)] = d;
    } else if (cls == 1) {
        int p = tid >> 2, qr = tid & 3;
        const float* src = &o_lds[p * 33 + (qr << 3)];
        uint4 d;
        d.x = pk2(src[0], src[1]); d.y = pk2(src[2], src[3]);
        d.z = pk2(src[4], src[5]); d.w = pk2(src[6], src[7]);
        *(uint4*)&KT[(((b << 10) + n0 + p) << 5) + (qr << 3)] = d;
    } else if (cls == 2) {
        // transpose: thread = (kd, octet of 8 positions), stride-33 cols
        int kd = tid >> 3, oc = tid & 7;
        const float* col = &o_lds[(oc << 3) * 33 + kd];
        uint4 d;
        d.x = pk2(col[0],   col[33]);  d.y = pk2(col[66],  col[99]);
        d.z = pk2(col[132], col[165]); d.w = pk2(col[198], col[231]);
        *(uint4*)&VW[((b << 5) + kd) * VWS + n0 + (oc << 3)] = d;
    } else {
        if (tid < 64) {
            const float* src = &o_lds[tid * 33];
            *(float2*)&QXY[((b << 10) + n0 + tid) << 1] = make_float2(src[0], src[1]);
            *(float2*)&KXY[((b << 10) + n0 + tid) << 1] = make_float2(src[2], src[3]);
        } else if (tid >= 128 && tid < 160 && (chunk & 15) == 15) {
            int kd = tid - 128;
            uint4 z = make_uint4(0, 0, 0, 0);
            *(uint4*)&VW[((b << 5) + kd) * VWS + 1024] = z;   // zero 8-u16 pad
        }
    }
}

// ---------- attention: 512 blocks = (b, 4x8-query tile); 4 waves = (m, kh) ----------
// UNCHANGED from round 5 (for clean timing attribution).
__global__ __launch_bounds__(256) void attn_kernel(
    const char* __restrict__ wsb, const float* __restrict__ Wout,
    float* __restrict__ out)
{
    const u16* QT = (const u16*)(wsb + WS_QT);
    const u16* KT = (const u16*)(wsb + WS_KT);
    const u16* VW = (const u16*)(wsb + WS_VW);
    const float* QXY = (const float*)(wsb + WS_QXY);
    const float* KXY = (const float*)(wsb + WS_KXY);

    __shared__ __align__(16) u16 kfr[20 * 64 * 8];   // K B-frags per region row
    __shared__ __align__(16) u16 vfr[20 * 64 * 8];   // V B-frags per (kk,nt)
    __shared__ __align__(16) u16 qfr[2 * 64 * 8];    // Q A-frags per m-tile
    __shared__ __align__(16) u16 wfr[4 * 64 * 8];    // Wout^T B-frags per nt
    __shared__ __align__(16) u16 Pl[32 * 328];       // P rows (stride 328)
    __shared__ __align__(16) float kxy2[320 * 2];
    __shared__ __align__(16) float qxy2[32 * 2];
    __shared__ __align__(16) float olds[32 * 36];    // O exchange (stride 36)
    __shared__ __align__(16) float mbuf[64];
    __shared__ __align__(16) float sbuf[64];

    int tid = threadIdx.x;
    int bid = blockIdx.x;
    int b = bid >> 5, t5 = bid & 31;
    int qy0 = (t5 >> 3) << 3;
    int qx0 = (t5 & 7) << 2;
    int ry0 = qy0 - 6, rx0 = qx0 - 6;

    // stage K fragments (1280 16B chunks); OOB clamped (masked later)
    #pragma unroll
    for (int i = 0; i < 5; i++) {
        int c = tid + i * 256;
        int slot = c >> 2, ch4 = c & 3;
        int sr = slot >> 4, sc = slot & 15;
        int n2 = (ry0 + sr) * 32 + rx0 + sc;
        n2 = max(0, min(1023, n2));
        uint4 d = *(const uint4*)(KT + ((((b << 10) + n2) << 5) + (ch4 << 3)));
        *(uint4*)&kfr[((sr << 6) + (ch4 << 4) + sc) << 3] = d;
    }
    // stage V fragments; VW rows padded to 1032 so spans never cross kd rows
    #pragma unroll
    for (int i = 0; i < 5; i++) {
        int c = tid + i * 256;
        int kk = c >> 7, r = c & 127;
        int nt = r >> 6, kg4 = (r >> 4) & 3, cl2 = r & 15;
        int kd = (nt << 4) + cl2;
        int slotb = (kk << 5) + (kg4 << 3);
        int ky2 = ry0 + (slotb >> 4);
        int n2b = ky2 * 32 + rx0 + (slotb & 15);
        if ((u32)ky2 > 31u) n2b = 0;
        const u32* src = (const u32*)(VW + ((b << 5) + kd) * VWS + n2b);
        uint4 d; d.x = src[0]; d.y = src[1]; d.z = src[2]; d.w = src[3];
        *(uint4*)&vfr[((((kk << 1) + nt) << 6) + (kg4 << 4) + cl2) << 3] = d;
    }
    // stage Q fragments
    if (tid < 128) {
        int mm = tid >> 6, l = tid & 63;
        int q = (mm << 4) + (l & 15);
        int nq = (qy0 + (q >> 2)) * 32 + qx0 + (q & 3);
        uint4 d = *(const uint4*)(QT + ((((b << 10) + nq) << 5) + ((l >> 4) << 3)));
        *(uint4*)&qfr[tid << 3] = d;
    }
    // stage Wout^T fragments (fp32 -> bf16)
    {
        int nt = tid >> 6, l = tid & 63;
        int cc = (nt << 4) + (l & 15);
        const float* wsrc = Wout + (cc << 5) + ((l >> 4) << 3);
        uint4 d;
        d.x = pk2(wsrc[0], wsrc[1]); d.y = pk2(wsrc[2], wsrc[3]);
        d.z = pk2(wsrc[4], wsrc[5]); d.w = pk2(wsrc[6], wsrc[7]);
        *(uint4*)&wfr[tid << 3] = d;
    }
    // stage kxy / qxy
    for (int i = tid; i < 320; i += 256) {
        int n2 = (ry0 + (i >> 4)) * 32 + rx0 + (i & 15);
        n2 = max(0, min(1023, n2));
        float2 v = *(const float2*)(KXY + (((b << 10) + n2) << 1));
        *(float2*)&kxy2[i << 1] = v;
    }
    if (tid < 32) {
        int nq = (qy0 + (tid >> 2)) * 32 + qx0 + (tid & 3);
        float2 v = *(const float2*)(QXY + (((b << 10) + nq) << 1));
        *(float2*)&qxy2[tid << 1] = v;
    }
    for (int i = tid; i < 32 * 36; i += 256) olds[i] = 0.f;

    __syncthreads();

    int wid = tid >> 6, ll = tid & 63;
    int m = wid & 1, kh = wid >> 1;
    int cl = ll & 15, kg = ll >> 4;

    // ---- QK^T: 10 MFMAs over this wave's 10 region rows
    bf16x8 aq = *(bf16x8*)&qfr[((m << 6) + ll) << 3];
    f32x4 acc[10];
    #pragma unroll
    for (int t = 0; t < 10; t++) {
        int rr = kh * 10 + t;
        bf16x8 bk = *(bf16x8*)&kfr[((rr << 6) + ll) << 3];
        f32x4 z = {0.f, 0.f, 0.f, 0.f};
        acc[t] = __builtin_amdgcn_mfma_f32_16x16x32_bf16(aq, bk, z, 0, 0, 0);
    }

    // ---- mask + xy scores + row max
    int qrl = (m << 2) + kg;            // query row within 8-row tile
    int dybase = kh * 10 - 6 - qrl;
    int kxv = rx0 + cl;
    bool kxok = (kxv >= 0) && (kxv < 32);
    float qa[4], qb[4]; int dx2c[4];
    #pragma unroll
    for (int r = 0; r < 4; r++) {
        int q = (m << 4) + (kg << 2) + r;
        float2 qv = *(float2*)&qxy2[q << 1];
        qa[r] = qv.x; qb[r] = qv.y;
        int dx = cl - 6 - r;
        dx2c[r] = dx * dx;
    }
    float mh[4] = {-1e30f, -1e30f, -1e30f, -1e30f};
    #pragma unroll
    for (int t = 0; t < 10; t++) {
        int rr = kh * 10 + t;
        int ky = ry0 + rr;
        bool kyok = (ky >= 0) && (ky < 32);
        float2 kv = *(float2*)&kxy2[((rr << 4) + cl) << 1];
        int dy = dybase + t, dy2 = dy * dy;
        #pragma unroll
        for (int r = 0; r < 4; r++) {
            float s = acc[t][r] + qa[r] * kv.x + qb[r] * kv.y;
            bool ok = kyok && kxok && (dy2 + dx2c[r] <= 36);
            acc[t][r] = ok ? s : -1e4f;
            mh[r] = fmaxf(mh[r], acc[t][r]);
        }
    }
    #pragma unroll
    for (int s = 1; s < 16; s <<= 1) {
        #pragma unroll
        for (int r = 0; r < 4; r++) mh[r] = fmaxf(mh[r], __shfl_xor(mh[r], s, 64));
    }
    if (cl == 0) {
        float4 t4 = make_float4(mh[0], mh[1], mh[2], mh[3]);
        *(float4*)&mbuf[(kh << 5) + (m << 4) + (kg << 2)] = t4;
    }
    __syncthreads();
    float4 om = *(float4*)&mbuf[((kh ^ 1) << 5) + (m << 4) + (kg << 2)];
    float mf[4];
    mf[0] = fmaxf(mh[0], om.x); mf[1] = fmaxf(mh[1], om.y);
    mf[2] = fmaxf(mh[2], om.z); mf[3] = fmaxf(mh[3], om.w);

    // ---- exp + row sum (cross-wave via sbuf), write P (bf16)
    float sh[4] = {0.f, 0.f, 0.f, 0.f};
    #pragma unroll
    for (int t = 0; t < 10; t++) {
        #pragma unroll
        for (int r = 0; r < 4; r++) {
            float p = __expf(acc[t][r] - mf[r]);
            acc[t][r] = p;
            sh[r] += p;
        }
    }
    #pragma unroll
    for (int s = 1; s < 16; s <<= 1) {
        #pragma unroll
        for (int r = 0; r < 4; r++) sh[r] += __shfl_xor(sh[r], s, 64);
    }
    if (cl == 0) {
        float4 t4 = make_float4(sh[0], sh[1], sh[2], sh[3]);
        *(float4*)&sbuf[(kh << 5) + (m << 4) + (kg << 2)] = t4;
    }
    #pragma unroll
    for (int t = 0; t < 10; t++) {
        int slot = ((kh * 10 + t) << 4) + cl;
        #pragma unroll
        for (int r = 0; r < 4; r++) {
            int q = (m << 4) + (kg << 2) + r;
            Pl[q * 328 + slot] = f2bf(acc[t][r]);
        }
    }
    __syncthreads();
    float4 os = *(float4*)&sbuf[((kh ^ 1) << 5) + (m << 4) + (kg << 2)];
    float rinv[4];
    rinv[0] = 1.f / (sh[0] + os.x); rinv[1] = 1.f / (sh[1] + os.y);
    rinv[2] = 1.f / (sh[2] + os.z); rinv[3] = 1.f / (sh[3] + os.w);

    // ---- PV: this wave's 5 k-tiles (its own P writes), 2 kd n-tiles
    f32x4 oacc0 = {0.f, 0.f, 0.f, 0.f}, oacc1 = {0.f, 0.f, 0.f, 0.f};
    int arow = (m << 4) + cl;
    #pragma unroll
    for (int i2 = 0; i2 < 5; i2++) {
        int kk = kh * 5 + i2;
        bf16x8 ap = *(bf16x8*)&Pl[arow * 328 + (kk << 5) + (kg << 3)];
        bf16x8 bv0 = *(bf16x8*)&vfr[(((kk << 1) << 6) + ll) << 3];
        bf16x8 bv1 = *(bf16x8*)&vfr[((((kk << 1) + 1) << 6) + ll) << 3];
        oacc0 = __builtin_amdgcn_mfma_f32_16x16x32_bf16(ap, bv0, oacc0, 0, 0, 0);
        oacc1 = __builtin_amdgcn_mfma_f32_16x16x32_bf16(ap, bv1, oacc1, 0, 0, 0);
    }
    // normalized partial-O accumulation across kh halves
    #pragma unroll
    for (int r = 0; r < 4; r++) {
        int q = (m << 4) + (kg << 2) + r;
        atomicAdd(&olds[q * 36 + cl],      oacc0[r] * rinv[r]);
        atomicAdd(&olds[q * 36 + cl + 16], oacc1[r] * rinv[r]);
    }
    __syncthreads();

    // ---- epilogue: Y = O * Wout^T via MFMA, scattered f32 stores
    int qe = (m << 4) + cl;
    float4 o1 = *(float4*)&olds[qe * 36 + (kg << 3)];
    float4 o2 = *(float4*)&olds[qe * 36 + (kg << 3) + 4];
    bf16x8 aO;
    aO[0] = (short)f2bf(o1.x); aO[1] = (short)f2bf(o1.y);
    aO[2] = (short)f2bf(o1.z); aO[3] = (short)f2bf(o1.w);
    aO[4] = (short)f2bf(o2.x); aO[5] = (short)f2bf(o2.y);
    aO[6] = (short)f2bf(o2.z); aO[7] = (short)f2bf(o2.w);

    int nqb = (qy0 + qrl) * 32 + qx0;
    #pragma unroll
    for (int e = 0; e < 2; e++) {
        int nt2 = (kh << 1) + e;
        bf16x8 bw = *(bf16x8*)&wfr[((nt2 << 6) + ll) << 3];
        f32x4 z = {0.f, 0.f, 0.f, 0.f};
        f32x4 y = __builtin_amdgcn_mfma_f32_16x16x32_bf16(aO, bw, z, 0, 0, 0);
        int cc = cl + (nt2 << 4);
        #pragma unroll
        for (int r = 0; r < 4; r++)
            out[(((b << 6) + cc) << 10) + nqb + r] = y[r];
    }
}

extern "C" void kernel_launch(void* const* d_in, const int* in_sizes, int n_in,
                              void* d_out, int out_size, void* d_ws, size_t ws_size,
                              hipStream_t stream) {
    const float* x    = (const float*)d_in[0];
    const float* Wq   = (const float*)d_in[1];
    const float* Wk   = (const float*)d_in[2];
    const float* Wv   = (const float*)d_in[3];
    const float* Wqxy = (const float*)d_in[4];
    const float* Wkxy = (const float*)d_in[5];
    const float* Wout = (const float*)d_in[6];
    float* out = (float*)d_out;
    char* wsb  = (char*)d_ws;

    proj_kernel<<<1024, 256, 0, stream>>>(x, Wq, Wk, Wv, Wqxy, Wkxy, wsb);
    attn_kernel<<<512, 256, 0, stream>>>(wsb, Wout, out);
}

// Round 7
// 56.363 us; speedup vs baseline: 1.4164x; 1.4164x over previous
//
#include <hip/hip_runtime.h>
#include <math.h>

typedef short bf16x8 __attribute__((ext_vector_type(8)));
typedef float f32x4 __attribute__((ext_vector_type(4)));
typedef unsigned short u16;
typedef unsigned int u32;

// ws byte offsets: QT (B,N,32) bf16, KT (B,N,32) bf16,
// VW (B,32,1032) bf16 (1024 + 8 pad per kd row, pad zeroed by proj),
// QXY (B,N,2) f32, KXY (B,N,2) f32
#define WS_QT  0
#define WS_KT  1048576
#define WS_VW  2097152
#define WS_QXY 3153920
#define WS_KXY 3284992
#define VWS    1032

__device__ __forceinline__ u16 f2bf(float f) {
    u32 u = __float_as_uint(f);
    u += 0x7fffu + ((u >> 16) & 1u);
    return (u16)(u >> 16);
}
__device__ __forceinline__ u32 pk2(float a, float b) {
    return (u32)f2bf(a) | ((u32)f2bf(b) << 16);
}

// ---------- projections: 256 blocks x 256 threads, split-K over channels ----
// wave = 16-channel quarter (readfirstlane'd -> scalar weight loads),
// lane = position. Each x byte read ONCE per block (coalesced). Cross-wave
// reduce via LDS lands wave q with j-range [25q,25q+25) for its lane ->
// identical (lane,jg) ownership to round-5's store rounds (reused verbatim).
__global__ __launch_bounds__(256) void proj_kernel(
    const float* __restrict__ x,
    const float* __restrict__ Wq, const float* __restrict__ Wk,
    const float* __restrict__ Wv, const float* __restrict__ Wqxy,
    const float* __restrict__ Wkxy, char* __restrict__ wsb)
{
    u16* QT = (u16*)(wsb + WS_QT);
    u16* KT = (u16*)(wsb + WS_KT);
    u16* VW = (u16*)(wsb + WS_VW);
    float* QXY = (float*)(wsb + WS_QXY);
    float* KXY = (float*)(wsb + WS_KXY);

    // aliased: buf[4][64][25] (6400 floats) then o_lds[64][101] (6464)
    __shared__ float sh[6464];

    int tid = threadIdx.x;
    int lane = tid & 63, q = tid >> 6;
    int b = blockIdx.x >> 4;
    int n0 = (blockIdx.x & 15) << 6;
    int n = n0 + lane;
    int rq = __builtin_amdgcn_readfirstlane(q);   // wave-uniform quarter

    // x: wave reads its 16-channel quarter, 64 contiguous floats per channel
    float xr[16];
    #pragma unroll
    for (int cc = 0; cc < 16; cc++)
        xr[cc] = x[(((b << 6) + (rq << 4) + cc) << 10) + n];

    // partial dots for all 100 j over this wave's quarter (w loads uniform)
    float p[100];
    #pragma unroll
    for (int j = 0; j < 100; j++) {
        const float* wrow;
        if (j < 32)      wrow = Wq   + (j << 6);
        else if (j < 64) wrow = Wk   + ((j - 32) << 6);
        else if (j < 96) wrow = Wv   + ((j - 64) << 6);
        else if (j < 98) wrow = Wqxy + ((j - 96) << 6);
        else             wrow = Wkxy + ((j - 98) << 6);
        const float4* w4 = (const float4*)(wrow + (rq << 4));
        float4 wa = w4[0], wb = w4[1], wc = w4[2], wd = w4[3];
        float a0 = wa.x * xr[0]  + wa.y * xr[1]  + wa.z * xr[2]  + wa.w * xr[3];
        float a1 = wb.x * xr[4]  + wb.y * xr[5]  + wb.z * xr[6]  + wb.w * xr[7];
        float a2 = wc.x * xr[8]  + wc.y * xr[9]  + wc.z * xr[10] + wc.w * xr[11];
        float a3 = wd.x * xr[12] + wd.y * xr[13] + wd.z * xr[14] + wd.w * xr[15];
        p[j] = (a0 + a1) + (a2 + a3);
    }

    // cross-wave reduce in 4 chunk rounds; wave r keeps j-range r in regs
    float o[25];
    #pragma unroll
    for (int r = 0; r < 4; r++) {
        __syncthreads();
        #pragma unroll
        for (int jj = 0; jj < 25; jj++)
            sh[((q << 6) + lane) * 25 + jj] = p[r * 25 + jj];
        __syncthreads();
        if (q == r) {
            #pragma unroll
            for (int jj = 0; jj < 25; jj++)
                o[jj] = (sh[lane * 25 + jj]          + sh[(64 + lane) * 25 + jj])
                      + (sh[(128 + lane) * 25 + jj]  + sh[(192 + lane) * 25 + jj]);
        }
    }
    __syncthreads();
    #pragma unroll
    for (int jj = 0; jj < 25; jj++)
        sh[lane * 101 + q * 25 + jj] = o[jj];
    __syncthreads();

    // ---- store rounds (round-5 verbatim; o_lds := sh, stride 101) ----
    // Round A: QT rows as contiguous uint4 chunks
    {
        int pp = tid >> 2, qr = tid & 3;
        const float* src = &sh[pp * 101 + (qr << 3)];
        uint4 d;
        d.x = pk2(src[0], src[1]); d.y = pk2(src[2], src[3]);
        d.z = pk2(src[4], src[5]); d.w = pk2(src[6], src[7]);
        *(uint4*)&QT[(((b << 10) + n0 + pp) << 5) + (qr << 3)] = d;
    }
    // Round B: KT
    {
        int pp = tid >> 2, qr = tid & 3;
        const float* src = &sh[pp * 101 + 32 + (qr << 3)];
        uint4 d;
        d.x = pk2(src[0], src[1]); d.y = pk2(src[2], src[3]);
        d.z = pk2(src[4], src[5]); d.w = pk2(src[6], src[7]);
        *(uint4*)&KT[(((b << 10) + n0 + pp) << 5) + (qr << 3)] = d;
    }
    // Round C: VW transposed: thread = (kd, octet of 8 positions)
    {
        int kd = tid >> 3, oc = tid & 7;
        const float* col = &sh[(oc << 3) * 101 + 64 + kd];
        uint4 d;
        d.x = pk2(col[0],   col[101]); d.y = pk2(col[202], col[303]);
        d.z = pk2(col[404], col[505]); d.w = pk2(col[606], col[707]);
        *(uint4*)&VW[((b << 5) + kd) * VWS + n0 + (oc << 3)] = d;
    }
    // Round D: QXY/KXY + VW row pads (one block per batch writes pads)
    if (tid < 64) {
        const float* src = &sh[tid * 101 + 96];
        *(float2*)&QXY[((b << 10) + n0 + tid) << 1] = make_float2(src[0], src[1]);
        *(float2*)&KXY[((b << 10) + n0 + tid) << 1] = make_float2(src[2], src[3]);
    } else if (tid >= 128 && tid < 160 && (blockIdx.x & 15) == 15) {
        int kd = tid - 128;
        uint4 z = make_uint4(0, 0, 0, 0);
        *(uint4*)&VW[((b << 5) + kd) * VWS + 1024] = z;   // zero 8-u16 pad
    }
}

// ---------- attention: 512 blocks = (b, 4x8-query tile); 4 waves = (m, kh) ----------
// UNCHANGED (for clean timing attribution).
__global__ __launch_bounds__(256) void attn_kernel(
    const char* __restrict__ wsb, const float* __restrict__ Wout,
    float* __restrict__ out)
{
    const u16* QT = (const u16*)(wsb + WS_QT);
    const u16* KT = (const u16*)(wsb + WS_KT);
    const u16* VW = (const u16*)(wsb + WS_VW);
    const float* QXY = (const float*)(wsb + WS_QXY);
    const float* KXY = (const float*)(wsb + WS_KXY);

    __shared__ __align__(16) u16 kfr[20 * 64 * 8];   // K B-frags per region row
    __shared__ __align__(16) u16 vfr[20 * 64 * 8];   // V B-frags per (kk,nt)
    __shared__ __align__(16) u16 qfr[2 * 64 * 8];    // Q A-frags per m-tile
    __shared__ __align__(16) u16 wfr[4 * 64 * 8];    // Wout^T B-frags per nt
    __shared__ __align__(16) u16 Pl[32 * 328];       // P rows (stride 328)
    __shared__ __align__(16) float kxy2[320 * 2];
    __shared__ __align__(16) float qxy2[32 * 2];
    __shared__ __align__(16) float olds[32 * 36];    // O exchange (stride 36)
    __shared__ __align__(16) float mbuf[64];
    __shared__ __align__(16) float sbuf[64];

    int tid = threadIdx.x;
    int bid = blockIdx.x;
    int b = bid >> 5, t5 = bid & 31;
    int qy0 = (t5 >> 3) << 3;
    int qx0 = (t5 & 7) << 2;
    int ry0 = qy0 - 6, rx0 = qx0 - 6;

    // stage K fragments (1280 16B chunks); OOB clamped (masked later)
    #pragma unroll
    for (int i = 0; i < 5; i++) {
        int c = tid + i * 256;
        int slot = c >> 2, ch4 = c & 3;
        int sr = slot >> 4, sc = slot & 15;
        int n2 = (ry0 + sr) * 32 + rx0 + sc;
        n2 = max(0, min(1023, n2));
        uint4 d = *(const uint4*)(KT + ((((b << 10) + n2) << 5) + (ch4 << 3)));
        *(uint4*)&kfr[((sr << 6) + (ch4 << 4) + sc) << 3] = d;
    }
    // stage V fragments; VW rows padded to 1032 so spans never cross kd rows
    #pragma unroll
    for (int i = 0; i < 5; i++) {
        int c = tid + i * 256;
        int kk = c >> 7, r = c & 127;
        int nt = r >> 6, kg4 = (r >> 4) & 3, cl2 = r & 15;
        int kd = (nt << 4) + cl2;
        int slotb = (kk << 5) + (kg4 << 3);
        int ky2 = ry0 + (slotb >> 4);
        int n2b = ky2 * 32 + rx0 + (slotb & 15);
        if ((u32)ky2 > 31u) n2b = 0;
        const u32* src = (const u32*)(VW + ((b << 5) + kd) * VWS + n2b);
        uint4 d; d.x = src[0]; d.y = src[1]; d.z = src[2]; d.w = src[3];
        *(uint4*)&vfr[((((kk << 1) + nt) << 6) + (kg4 << 4) + cl2) << 3] = d;
    }
    // stage Q fragments
    if (tid < 128) {
        int mm = tid >> 6, l = tid & 63;
        int q = (mm << 4) + (l & 15);
        int nq = (qy0 + (q >> 2)) * 32 + qx0 + (q & 3);
        uint4 d = *(const uint4*)(QT + ((((b << 10) + nq) << 5) + ((l >> 4) << 3)));
        *(uint4*)&qfr[tid << 3] = d;
    }
    // stage Wout^T fragments (fp32 -> bf16)
    {
        int nt = tid >> 6, l = tid & 63;
        int cc = (nt << 4) + (l & 15);
        const float* wsrc = Wout + (cc << 5) + ((l >> 4) << 3);
        uint4 d;
        d.x = pk2(wsrc[0], wsrc[1]); d.y = pk2(wsrc[2], wsrc[3]);
        d.z = pk2(wsrc[4], wsrc[5]); d.w = pk2(wsrc[6], wsrc[7]);
        *(uint4*)&wfr[tid << 3] = d;
    }
    // stage kxy / qxy
    for (int i = tid; i < 320; i += 256) {
        int n2 = (ry0 + (i >> 4)) * 32 + rx0 + (i & 15);
        n2 = max(0, min(1023, n2));
        float2 v = *(const float2*)(KXY + (((b << 10) + n2) << 1));
        *(float2*)&kxy2[i << 1] = v;
    }
    if (tid < 32) {
        int nq = (qy0 + (tid >> 2)) * 32 + qx0 + (tid & 3);
        float2 v = *(const float2*)(QXY + (((b << 10) + nq) << 1));
        *(float2*)&qxy2[tid << 1] = v;
    }
    for (int i = tid; i < 32 * 36; i += 256) olds[i] = 0.f;

    __syncthreads();

    int wid = tid >> 6, ll = tid & 63;
    int m = wid & 1, kh = wid >> 1;
    int cl = ll & 15, kg = ll >> 4;

    // ---- QK^T: 10 MFMAs over this wave's 10 region rows
    bf16x8 aq = *(bf16x8*)&qfr[((m << 6) + ll) << 3];
    f32x4 acc[10];
    #pragma unroll
    for (int t = 0; t < 10; t++) {
        int rr = kh * 10 + t;
        bf16x8 bk = *(bf16x8*)&kfr[((rr << 6) + ll) << 3];
        f32x4 z = {0.f, 0.f, 0.f, 0.f};
        acc[t] = __builtin_amdgcn_mfma_f32_16x16x32_bf16(aq, bk, z, 0, 0, 0);
    }

    // ---- mask + xy scores + row max
    int qrl = (m << 2) + kg;            // query row within 8-row tile
    int dybase = kh * 10 - 6 - qrl;
    int kxv = rx0 + cl;
    bool kxok = (kxv >= 0) && (kxv < 32);
    float qa[4], qb[4]; int dx2c[4];
    #pragma unroll
    for (int r = 0; r < 4; r++) {
        int q = (m << 4) + (kg << 2) + r;
        float2 qv = *(float2*)&qxy2[q << 1];
        qa[r] = qv.x; qb[r] = qv.y;
        int dx = cl - 6 - r;
        dx2c[r] = dx * dx;
    }
    float mh[4] = {-1e30f, -1e30f, -1e30f, -1e30f};
    #pragma unroll
    for (int t = 0; t < 10; t++) {
        int rr = kh * 10 + t;
        int ky = ry0 + rr;
        bool kyok = (ky >= 0) && (ky < 32);
        float2 kv = *(float2*)&kxy2[((rr << 4) + cl) << 1];
        int dy = dybase + t, dy2 = dy * dy;
        #pragma unroll
        for (int r = 0; r < 4; r++) {
            float s = acc[t][r] + qa[r] * kv.x + qb[r] * kv.y;
            bool ok = kyok && kxok && (dy2 + dx2c[r] <= 36);
            acc[t][r] = ok ? s : -1e4f;
            mh[r] = fmaxf(mh[r], acc[t][r]);
        }
    }
    #pragma unroll
    for (int s = 1; s < 16; s <<= 1) {
        #pragma unroll
        for (int r = 0; r < 4; r++) mh[r] = fmaxf(mh[r], __shfl_xor(mh[r], s, 64));
    }
    if (cl == 0) {
        float4 t4 = make_float4(mh[0], mh[1], mh[2], mh[3]);
        *(float4*)&mbuf[(kh << 5) + (m << 4) + (kg << 2)] = t4;
    }
    __syncthreads();
    float4 om = *(float4*)&mbuf[((kh ^ 1) << 5) + (m << 4) + (kg << 2)];
    float mf[4];
    mf[0] = fmaxf(mh[0], om.x); mf[1] = fmaxf(mh[1], om.y);
    mf[2] = fmaxf(mh[2], om.z); mf[3] = fmaxf(mh[3], om.w);

    // ---- exp + row sum (cross-wave via sbuf), write P (bf16)
    float sh4[4] = {0.f, 0.f, 0.f, 0.f};
    #pragma unroll
    for (int t = 0; t < 10; t++) {
        #pragma unroll
        for (int r = 0; r < 4; r++) {
            float p = __expf(acc[t][r] - mf[r]);
            acc[t][r] = p;
            sh4[r] += p;
        }
    }
    #pragma unroll
    for (int s = 1; s < 16; s <<= 1) {
        #pragma unroll
        for (int r = 0; r < 4; r++) sh4[r] += __shfl_xor(sh4[r], s, 64);
    }
    if (cl == 0) {
        float4 t4 = make_float4(sh4[0], sh4[1], sh4[2], sh4[3]);
        *(float4*)&sbuf[(kh << 5) + (m << 4) + (kg << 2)] = t4;
    }
    #pragma unroll
    for (int t = 0; t < 10; t++) {
        int slot = ((kh * 10 + t) << 4) + cl;
        #pragma unroll
        for (int r = 0; r < 4; r++) {
            int q = (m << 4) + (kg << 2) + r;
            Pl[q * 328 + slot] = f2bf(acc[t][r]);
        }
    }
    __syncthreads();
    float4 os = *(float4*)&sbuf[((kh ^ 1) << 5) + (m << 4) + (kg << 2)];
    float rinv[4];
    rinv[0] = 1.f / (sh4[0] + os.x); rinv[1] = 1.f / (sh4[1] + os.y);
    rinv[2] = 1.f / (sh4[2] + os.z); rinv[3] = 1.f / (sh4[3] + os.w);

    // ---- PV: this wave's 5 k-tiles (its own P writes), 2 kd n-tiles
    f32x4 oacc0 = {0.f, 0.f, 0.f, 0.f}, oacc1 = {0.f, 0.f, 0.f, 0.f};
    int arow = (m << 4) + cl;
    #pragma unroll
    for (int i2 = 0; i2 < 5; i2++) {
        int kk = kh * 5 + i2;
        bf16x8 ap = *(bf16x8*)&Pl[arow * 328 + (kk << 5) + (kg << 3)];
        bf16x8 bv0 = *(bf16x8*)&vfr[(((kk << 1) << 6) + ll) << 3];
        bf16x8 bv1 = *(bf16x8*)&vfr[((((kk << 1) + 1) << 6) + ll) << 3];
        oacc0 = __builtin_amdgcn_mfma_f32_16x16x32_bf16(ap, bv0, oacc0, 0, 0, 0);
        oacc1 = __builtin_amdgcn_mfma_f32_16x16x32_bf16(ap, bv1, oacc1, 0, 0, 0);
    }
    // normalized partial-O accumulation across kh halves
    #pragma unroll
    for (int r = 0; r < 4; r++) {
        int q = (m << 4) + (kg << 2) + r;
        atomicAdd(&olds[q * 36 + cl],      oacc0[r] * rinv[r]);
        atomicAdd(&olds[q * 36 + cl + 16], oacc1[r] * rinv[r]);
    }
    __syncthreads();

    // ---- epilogue: Y = O * Wout^T via MFMA, scattered f32 stores
    int qe = (m << 4) + cl;
    float4 o1 = *(float4*)&olds[qe * 36 + (kg << 3)];
    float4 o2 = *(float4*)&olds[qe * 36 + (kg << 3) + 4];
    bf16x8 aO;
    aO[0] = (short)f2bf(o1.x); aO[1] = (short)f2bf(o1.y);
    aO[2] = (short)f2bf(o1.z); aO[3] = (short)f2bf(o1.w);
    aO[4] = (short)f2bf(o2.x); aO[5] = (short)f2bf(o2.y);
    aO[6] = (short)f2bf(o2.z); aO[7] = (short)f2bf(o2.w);

    int nqb = (qy0 + qrl) * 32 + qx0;
    #pragma unroll
    for (int e = 0; e < 2; e++) {
        int nt2 = (kh << 1) + e;
        bf16x8 bw = *(bf16x8*)&wfr[((nt2 << 6) + ll) << 3];
        f32x4 z = {0.f, 0.f, 0.f, 0.f};
        f32x4 y = __builtin_amdgcn_mfma_f32_16x16x32_bf16(aO, bw, z, 0, 0, 0);
        int cc = cl + (nt2 << 4);
        #pragma unroll
        for (int r = 0; r < 4; r++)
            out[(((b << 6) + cc) << 10) + nqb + r] = y[r];
    }
}

extern "C" void kernel_launch(void* const* d_in, const int* in_sizes, int n_in,
                              void* d_out, int out_size, void* d_ws, size_t ws_size,
                              hipStream_t stream) {
    const float* x    = (const float*)d_in[0];
    const float* Wq   = (const float*)d_in[1];
    const float* Wk   = (const float*)d_in[2];
    const float* Wv   = (const float*)d_in[3];
    const float* Wqxy = (const float*)d_in[4];
    const float* Wkxy = (const float*)d_in[5];
    const float* Wout = (const float*)d_in[6];
    float* out = (float*)d_out;
    char* wsb  = (char*)d_ws;

    proj_kernel<<<256, 256, 0, stream>>>(x, Wq, Wk, Wv, Wqxy, Wkxy, wsb);
    attn_kernel<<<512, 256, 0, stream>>>(wsb, Wout, out);
}

// Round 8
// 30.468 us; speedup vs baseline: 2.6201x; 1.8499x over previous
//
#include <hip/hip_runtime.h>
#include <math.h>

typedef short bf16x8 __attribute__((ext_vector_type(8)));
typedef float f32x4 __attribute__((ext_vector_type(4)));
typedef unsigned short u16;
typedef unsigned int u32;

// ws byte offsets: QT (B,N,32) bf16, KT (B,N,32) bf16,
// VW (B,32,1032) bf16 (1024 + 8 pad per kd row, pad zeroed by proj),
// QXY (B,N,2) f32, KXY (B,N,2) f32
#define WS_QT  0
#define WS_KT  1048576
#define WS_VW  2097152
#define WS_QXY 3153920
#define WS_KXY 3284992
#define VWS    1032

__device__ __forceinline__ u16 f2bf(float f) {
    u32 u = __float_as_uint(f);
    u += 0x7fffu + ((u >> 16) & 1u);
    return (u16)(u >> 16);
}
__device__ __forceinline__ u32 pk2(float a, float b) {
    return (u32)f2bf(a) | ((u32)f2bf(b) << 16);
}

// ---------- projections as MFMA GEMM: 1024 one-wave blocks ----------
// wave = 16 positions x 112 j-cols (7 tiles of 16). Out[n,j] = sum_c x[c,n]W[j,c].
// A = x^T (hi/lo bf16 split), B = W^T (hi/lo split); acc = xh*wh + xl*wh + xh*wl
// (error ~2^-15 ~= fp32). A/B staged with identical per-lane k maps (k-perm
// cancels); C/D (HW-verified): col=lane&15, row=(lane>>4)*4+reg.
__global__ __launch_bounds__(64) void proj_kernel(
    const float* __restrict__ x,
    const float* __restrict__ Wq, const float* __restrict__ Wk,
    const float* __restrict__ Wv, const float* __restrict__ Wqxy,
    const float* __restrict__ Wkxy, char* __restrict__ wsb)
{
    u16* QT = (u16*)(wsb + WS_QT);
    u16* KT = (u16*)(wsb + WS_KT);
    u16* VW = (u16*)(wsb + WS_VW);
    float* QXY = (float*)(wsb + WS_QXY);
    float* KXY = (float*)(wsb + WS_KXY);

    int l = threadIdx.x;
    int g = l >> 4, l15 = l & 15;
    int bid = blockIdx.x;
    int b = bid >> 6, n0 = (bid & 63) << 4;

    // A-fragments: x^T[n][c] with c = ks*32 + g*8 + i; coalesced (16 consecutive
    // n per lane-group, 4 channel-rows per load instruction). hi/lo bf16 split.
    bf16x8 ah[2], al[2];
    #pragma unroll
    for (int ks = 0; ks < 2; ks++) {
        float av[8];
        #pragma unroll
        for (int i = 0; i < 8; i++)
            av[i] = x[(((b << 6) + (ks << 5) + (g << 3) + i) << 10) + n0 + l15];
        #pragma unroll
        for (int i = 0; i < 8; i++) {
            u16 hb = f2bf(av[i]);
            float rr = av[i] - __uint_as_float((u32)hb << 16);
            ah[ks][i] = (short)hb;
            al[ks][i] = (short)f2bf(rr);
        }
    }

    #pragma unroll
    for (int jt = 0; jt < 7; jt++) {
        f32x4 acc = {0.f, 0.f, 0.f, 0.f};
        #pragma unroll
        for (int ks = 0; ks < 2; ks++) {
            float wv[8];
            #pragma unroll
            for (int i = 0; i < 8; i++) wv[i] = 0.f;
            if (jt < 6) {
                const float* wbase = (jt < 2) ? Wq : (jt < 4) ? Wk : Wv;
                const float* wr = wbase + ((((jt & 1) << 4) + l15) << 6)
                                        + (ks << 5) + (g << 3);
                float4 wa = *(const float4*)wr, wb = *(const float4*)(wr + 4);
                wv[0] = wa.x; wv[1] = wa.y; wv[2] = wa.z; wv[3] = wa.w;
                wv[4] = wb.x; wv[5] = wb.y; wv[6] = wb.z; wv[7] = wb.w;
            } else if (l15 < 4) {
                const float* wr = ((l15 < 2) ? (Wqxy + (l15 << 6))
                                             : (Wkxy + ((l15 - 2) << 6)))
                                  + (ks << 5) + (g << 3);
                float4 wa = *(const float4*)wr, wb = *(const float4*)(wr + 4);
                wv[0] = wa.x; wv[1] = wa.y; wv[2] = wa.z; wv[3] = wa.w;
                wv[4] = wb.x; wv[5] = wb.y; wv[6] = wb.z; wv[7] = wb.w;
            }
            bf16x8 wh, wl;
            #pragma unroll
            for (int i = 0; i < 8; i++) {
                u16 hb = f2bf(wv[i]);
                float rr = wv[i] - __uint_as_float((u32)hb << 16);
                wh[i] = (short)hb;
                wl[i] = (short)f2bf(rr);
            }
            acc = __builtin_amdgcn_mfma_f32_16x16x32_bf16(ah[ks], wh, acc, 0, 0, 0);
            acc = __builtin_amdgcn_mfma_f32_16x16x32_bf16(al[ks], wh, acc, 0, 0, 0);
            acc = __builtin_amdgcn_mfma_f32_16x16x32_bf16(ah[ks], wl, acc, 0, 0, 0);
        }
        // stores: C/D row = n0 + g*4 + r, col = l15
        if (jt < 2) {
            #pragma unroll
            for (int r = 0; r < 4; r++)
                QT[(((b << 10) + n0 + (g << 2) + r) << 5) + (jt << 4) + l15]
                    = f2bf(acc[r]);
        } else if (jt < 4) {
            #pragma unroll
            for (int r = 0; r < 4; r++)
                KT[(((b << 10) + n0 + (g << 2) + r) << 5) + ((jt - 2) << 4) + l15]
                    = f2bf(acc[r]);
        } else if (jt < 6) {
            int kd = ((jt - 4) << 4) + l15;
            uint2 d = make_uint2(pk2(acc[0], acc[1]), pk2(acc[2], acc[3]));
            *(uint2*)&VW[((b << 5) + kd) * VWS + n0 + (g << 2)] = d;
        } else {
            if (l15 < 2) {
                #pragma unroll
                for (int r = 0; r < 4; r++)
                    QXY[(((b << 10) + n0 + (g << 2) + r) << 1) + l15] = acc[r];
            } else if (l15 < 4) {
                #pragma unroll
                for (int r = 0; r < 4; r++)
                    KXY[(((b << 10) + n0 + (g << 2) + r) << 1) + (l15 - 2)] = acc[r];
            }
        }
    }

    // zero the VW row pads (8 u16 per kd row), one block per batch
    if ((bid & 63) == 63 && l < 32)
        *(uint4*)&VW[((b << 5) + l) * VWS + 1024] = make_uint4(0, 0, 0, 0);
}

// ---------- attention: 512 blocks = (b, 4x8-query tile); 4 waves = (m, kh) ----------
// UNCHANGED (for clean timing attribution).
__global__ __launch_bounds__(256) void attn_kernel(
    const char* __restrict__ wsb, const float* __restrict__ Wout,
    float* __restrict__ out)
{
    const u16* QT = (const u16*)(wsb + WS_QT);
    const u16* KT = (const u16*)(wsb + WS_KT);
    const u16* VW = (const u16*)(wsb + WS_VW);
    const float* QXY = (const float*)(wsb + WS_QXY);
    const float* KXY = (const float*)(wsb + WS_KXY);

    __shared__ __align__(16) u16 kfr[20 * 64 * 8];   // K B-frags per region row
    __shared__ __align__(16) u16 vfr[20 * 64 * 8];   // V B-frags per (kk,nt)
    __shared__ __align__(16) u16 qfr[2 * 64 * 8];    // Q A-frags per m-tile
    __shared__ __align__(16) u16 wfr[4 * 64 * 8];    // Wout^T B-frags per nt
    __shared__ __align__(16) u16 Pl[32 * 328];       // P rows (stride 328)
    __shared__ __align__(16) float kxy2[320 * 2];
    __shared__ __align__(16) float qxy2[32 * 2];
    __shared__ __align__(16) float olds[32 * 36];    // O exchange (stride 36)
    __shared__ __align__(16) float mbuf[64];
    __shared__ __align__(16) float sbuf[64];

    int tid = threadIdx.x;
    int bid = blockIdx.x;
    int b = bid >> 5, t5 = bid & 31;
    int qy0 = (t5 >> 3) << 3;
    int qx0 = (t5 & 7) << 2;
    int ry0 = qy0 - 6, rx0 = qx0 - 6;

    // stage K fragments (1280 16B chunks); OOB clamped (masked later)
    #pragma unroll
    for (int i = 0; i < 5; i++) {
        int c = tid + i * 256;
        int slot = c >> 2, ch4 = c & 3;
        int sr = slot >> 4, sc = slot & 15;
        int n2 = (ry0 + sr) * 32 + rx0 + sc;
        n2 = max(0, min(1023, n2));
        uint4 d = *(const uint4*)(KT + ((((b << 10) + n2) << 5) + (ch4 << 3)));
        *(uint4*)&kfr[((sr << 6) + (ch4 << 4) + sc) << 3] = d;
    }
    // stage V fragments; VW rows padded to 1032 so spans never cross kd rows
    #pragma unroll
    for (int i = 0; i < 5; i++) {
        int c = tid + i * 256;
        int kk = c >> 7, r = c & 127;
        int nt = r >> 6, kg4 = (r >> 4) & 3, cl2 = r & 15;
        int kd = (nt << 4) + cl2;
        int slotb = (kk << 5) + (kg4 << 3);
        int ky2 = ry0 + (slotb >> 4);
        int n2b = ky2 * 32 + rx0 + (slotb & 15);
        if ((u32)ky2 > 31u) n2b = 0;
        const u32* src = (const u32*)(VW + ((b << 5) + kd) * VWS + n2b);
        uint4 d; d.x = src[0]; d.y = src[1]; d.z = src[2]; d.w = src[3];
        *(uint4*)&vfr[((((kk << 1) + nt) << 6) + (kg4 << 4) + cl2) << 3] = d;
    }
    // stage Q fragments
    if (tid < 128) {
        int mm = tid >> 6, l = tid & 63;
        int q = (mm << 4) + (l & 15);
        int nq = (qy0 + (q >> 2)) * 32 + qx0 + (q & 3);
        uint4 d = *(const uint4*)(QT + ((((b << 10) + nq) << 5) + ((l >> 4) << 3)));
        *(uint4*)&qfr[tid << 3] = d;
    }
    // stage Wout^T fragments (fp32 -> bf16)
    {
        int nt = tid >> 6, l = tid & 63;
        int cc = (nt << 4) + (l & 15);
        const float* wsrc = Wout + (cc << 5) + ((l >> 4) << 3);
        uint4 d;
        d.x = pk2(wsrc[0], wsrc[1]); d.y = pk2(wsrc[2], wsrc[3]);
        d.z = pk2(wsrc[4], wsrc[5]); d.w = pk2(wsrc[6], wsrc[7]);
        *(uint4*)&wfr[tid << 3] = d;
    }
    // stage kxy / qxy
    for (int i = tid; i < 320; i += 256) {
        int n2 = (ry0 + (i >> 4)) * 32 + rx0 + (i & 15);
        n2 = max(0, min(1023, n2));
        float2 v = *(const float2*)(KXY + (((b << 10) + n2) << 1));
        *(float2*)&kxy2[i << 1] = v;
    }
    if (tid < 32) {
        int nq = (qy0 + (tid >> 2)) * 32 + qx0 + (tid & 3);
        float2 v = *(const float2*)(QXY + (((b << 10) + nq) << 1));
        *(float2*)&qxy2[tid << 1] = v;
    }
    for (int i = tid; i < 32 * 36; i += 256) olds[i] = 0.f;

    __syncthreads();

    int wid = tid >> 6, ll = tid & 63;
    int m = wid & 1, kh = wid >> 1;
    int cl = ll & 15, kg = ll >> 4;

    // ---- QK^T: 10 MFMAs over this wave's 10 region rows
    bf16x8 aq = *(bf16x8*)&qfr[((m << 6) + ll) << 3];
    f32x4 acc[10];
    #pragma unroll
    for (int t = 0; t < 10; t++) {
        int rr = kh * 10 + t;
        bf16x8 bk = *(bf16x8*)&kfr[((rr << 6) + ll) << 3];
        f32x4 z = {0.f, 0.f, 0.f, 0.f};
        acc[t] = __builtin_amdgcn_mfma_f32_16x16x32_bf16(aq, bk, z, 0, 0, 0);
    }

    // ---- mask + xy scores + row max
    int qrl = (m << 2) + kg;            // query row within 8-row tile
    int dybase = kh * 10 - 6 - qrl;
    int kxv = rx0 + cl;
    bool kxok = (kxv >= 0) && (kxv < 32);
    float qa[4], qb[4]; int dx2c[4];
    #pragma unroll
    for (int r = 0; r < 4; r++) {
        int q = (m << 4) + (kg << 2) + r;
        float2 qv = *(float2*)&qxy2[q << 1];
        qa[r] = qv.x; qb[r] = qv.y;
        int dx = cl - 6 - r;
        dx2c[r] = dx * dx;
    }
    float mh[4] = {-1e30f, -1e30f, -1e30f, -1e30f};
    #pragma unroll
    for (int t = 0; t < 10; t++) {
        int rr = kh * 10 + t;
        int ky = ry0 + rr;
        bool kyok = (ky >= 0) && (ky < 32);
        float2 kv = *(float2*)&kxy2[((rr << 4) + cl) << 1];
        int dy = dybase + t, dy2 = dy * dy;
        #pragma unroll
        for (int r = 0; r < 4; r++) {
            float s = acc[t][r] + qa[r] * kv.x + qb[r] * kv.y;
            bool ok = kyok && kxok && (dy2 + dx2c[r] <= 36);
            acc[t][r] = ok ? s : -1e4f;
            mh[r] = fmaxf(mh[r], acc[t][r]);
        }
    }
    #pragma unroll
    for (int s = 1; s < 16; s <<= 1) {
        #pragma unroll
        for (int r = 0; r < 4; r++) mh[r] = fmaxf(mh[r], __shfl_xor(mh[r], s, 64));
    }
    if (cl == 0) {
        float4 t4 = make_float4(mh[0], mh[1], mh[2], mh[3]);
        *(float4*)&mbuf[(kh << 5) + (m << 4) + (kg << 2)] = t4;
    }
    __syncthreads();
    float4 om = *(float4*)&mbuf[((kh ^ 1) << 5) + (m << 4) + (kg << 2)];
    float mf[4];
    mf[0] = fmaxf(mh[0], om.x); mf[1] = fmaxf(mh[1], om.y);
    mf[2] = fmaxf(mh[2], om.z); mf[3] = fmaxf(mh[3], om.w);

    // ---- exp + row sum (cross-wave via sbuf), write P (bf16)
    float sh4[4] = {0.f, 0.f, 0.f, 0.f};
    #pragma unroll
    for (int t = 0; t < 10; t++) {
        #pragma unroll
        for (int r = 0; r < 4; r++) {
            float p = __expf(acc[t][r] - mf[r]);
            acc[t][r] = p;
            sh4[r] += p;
        }
    }
    #pragma unroll
    for (int s = 1; s < 16; s <<= 1) {
        #pragma unroll
        for (int r = 0; r < 4; r++) sh4[r] += __shfl_xor(sh4[r], s, 64);
    }
    if (cl == 0) {
        float4 t4 = make_float4(sh4[0], sh4[1], sh4[2], sh4[3]);
        *(float4*)&sbuf[(kh << 5) + (m << 4) + (kg << 2)] = t4;
    }
    #pragma unroll
    for (int t = 0; t < 10; t++) {
        int slot = ((kh * 10 + t) << 4) + cl;
        #pragma unroll
        for (int r = 0; r < 4; r++) {
            int q = (m << 4) + (kg << 2) + r;
            Pl[q * 328 + slot] = f2bf(acc[t][r]);
        }
    }
    __syncthreads();
    float4 os = *(float4*)&sbuf[((kh ^ 1) << 5) + (m << 4) + (kg << 2)];
    float rinv[4];
    rinv[0] = 1.f / (sh4[0] + os.x); rinv[1] = 1.f / (sh4[1] + os.y);
    rinv[2] = 1.f / (sh4[2] + os.z); rinv[3] = 1.f / (sh4[3] + os.w);

    // ---- PV: this wave's 5 k-tiles (its own P writes), 2 kd n-tiles
    f32x4 oacc0 = {0.f, 0.f, 0.f, 0.f}, oacc1 = {0.f, 0.f, 0.f, 0.f};
    int arow = (m << 4) + cl;
    #pragma unroll
    for (int i2 = 0; i2 < 5; i2++) {
        int kk = kh * 5 + i2;
        bf16x8 ap = *(bf16x8*)&Pl[arow * 328 + (kk << 5) + (kg << 3)];
        bf16x8 bv0 = *(bf16x8*)&vfr[(((kk << 1) << 6) + ll) << 3];
        bf16x8 bv1 = *(bf16x8*)&vfr[((((kk << 1) + 1) << 6) + ll) << 3];
        oacc0 = __builtin_amdgcn_mfma_f32_16x16x32_bf16(ap, bv0, oacc0, 0, 0, 0);
        oacc1 = __builtin_amdgcn_mfma_f32_16x16x32_bf16(ap, bv1, oacc1, 0, 0, 0);
    }
    // normalized partial-O accumulation across kh halves
    #pragma unroll
    for (int r = 0; r < 4; r++) {
        int q = (m << 4) + (kg << 2) + r;
        atomicAdd(&olds[q * 36 + cl],      oacc0[r] * rinv[r]);
        atomicAdd(&olds[q * 36 + cl + 16], oacc1[r] * rinv[r]);
    }
    __syncthreads();

    // ---- epilogue: Y = O * Wout^T via MFMA, scattered f32 stores
    int qe = (m << 4) + cl;
    float4 o1 = *(float4*)&olds[qe * 36 + (kg << 3)];
    float4 o2 = *(float4*)&olds[qe * 36 + (kg << 3) + 4];
    bf16x8 aO;
    aO[0] = (short)f2bf(o1.x); aO[1] = (short)f2bf(o1.y);
    aO[2] = (short)f2bf(o1.z); aO[3] = (short)f2bf(o1.w);
    aO[4] = (short)f2bf(o2.x); aO[5] = (short)f2bf(o2.y);
    aO[6] = (short)f2bf(o2.z); aO[7] = (short)f2bf(o2.w);

    int nqb = (qy0 + qrl) * 32 + qx0;
    #pragma unroll
    for (int e = 0; e < 2; e++) {
        int nt2 = (kh << 1) + e;
        bf16x8 bw = *(bf16x8*)&wfr[((nt2 << 6) + ll) << 3];
        f32x4 z = {0.f, 0.f, 0.f, 0.f};
        f32x4 y = __builtin_amdgcn_mfma_f32_16x16x32_bf16(aO, bw, z, 0, 0, 0);
        int cc = cl + (nt2 << 4);
        #pragma unroll
        for (int r = 0; r < 4; r++)
            out[(((b << 6) + cc) << 10) + nqb + r] = y[r];
    }
}

extern "C" void kernel_launch(void* const* d_in, const int* in_sizes, int n_in,
                              void* d_out, int out_size, void* d_ws, size_t ws_size,
                              hipStream_t stream) {
    const float* x    = (const float*)d_in[0];
    const float* Wq   = (const float*)d_in[1];
    const float* Wk   = (const float*)d_in[2];
    const float* Wv   = (const float*)d_in[3];
    const float* Wqxy = (const float*)d_in[4];
    const float* Wkxy = (const float*)d_in[5];
    const float* Wout = (const float*)d_in[6];
    float* out = (float*)d_out;
    char* wsb  = (char*)d_ws;

    proj_kernel<<<1024, 64, 0, stream>>>(x, Wq, Wk, Wv, Wqxy, Wkxy, wsb);
    attn_kernel<<<512, 256, 0, stream>>>(wsb, Wout, out);
}

// Round 10
// 26.019 us; speedup vs baseline: 3.0681x; 1.1710x over previous
//
#include <hip/hip_runtime.h>
#include <math.h>

typedef short bf16x8 __attribute__((ext_vector_type(8)));
typedef float f32x4 __attribute__((ext_vector_type(4)));
typedef unsigned short u16;
typedef unsigned int u32;

// ws byte offsets: QT (B,N,32) bf16, KT (B,N,32) bf16,
// VW (B,32,1032) bf16 (1024 + 8 pad per kd row, pad zeroed by proj),
// QXY (B,N,2) f32, KXY (B,N,2) f32
#define WS_QT  0
#define WS_KT  1048576
#define WS_VW  2097152
#define WS_QXY 3153920
#define WS_KXY 3284992
#define VWS    1032

__device__ __forceinline__ u32 f2bf(float f) {
    u32 u = __float_as_uint(f);
    u += 0x7fffu + ((u >> 16) & 1u);
    return u >> 16;
}
__device__ __forceinline__ u32 pk2(float a, float b) {
    return f2bf(a) | (f2bf(b) << 16);
}

union U4H { uint4 u; bf16x8 h; };

// ---------- projections as MFMA GEMM: 1024 one-wave blocks (round-8, kept) ----------
__global__ __launch_bounds__(64) void proj_kernel(
    const float* __restrict__ x,
    const float* __restrict__ Wq, const float* __restrict__ Wk,
    const float* __restrict__ Wv, const float* __restrict__ Wqxy,
    const float* __restrict__ Wkxy, char* __restrict__ wsb)
{
    u16* QT = (u16*)(wsb + WS_QT);
    u16* KT = (u16*)(wsb + WS_KT);
    u16* VW = (u16*)(wsb + WS_VW);
    float* QXY = (float*)(wsb + WS_QXY);
    float* KXY = (float*)(wsb + WS_KXY);

    int l = threadIdx.x;
    int g = l >> 4, l15 = l & 15;
    int bid = blockIdx.x;
    int b = bid >> 6, n0 = (bid & 63) << 4;

    bf16x8 ah[2], al[2];
    #pragma unroll
    for (int ks = 0; ks < 2; ks++) {
        float av[8];
        #pragma unroll
        for (int i = 0; i < 8; i++)
            av[i] = x[(((b << 6) + (ks << 5) + (g << 3) + i) << 10) + n0 + l15];
        #pragma unroll
        for (int i = 0; i < 8; i++) {
            u32 hb = f2bf(av[i]);
            float rr = av[i] - __uint_as_float(hb << 16);
            ah[ks][i] = (short)hb;
            al[ks][i] = (short)f2bf(rr);
        }
    }

    #pragma unroll
    for (int jt = 0; jt < 7; jt++) {
        f32x4 acc = {0.f, 0.f, 0.f, 0.f};
        #pragma unroll
        for (int ks = 0; ks < 2; ks++) {
            float wv[8];
            #pragma unroll
            for (int i = 0; i < 8; i++) wv[i] = 0.f;
            if (jt < 6) {
                const float* wbase = (jt < 2) ? Wq : (jt < 4) ? Wk : Wv;
                const float* wr = wbase + ((((jt & 1) << 4) + l15) << 6)
                                        + (ks << 5) + (g << 3);
                float4 wa = *(const float4*)wr, wb = *(const float4*)(wr + 4);
                wv[0] = wa.x; wv[1] = wa.y; wv[2] = wa.z; wv[3] = wa.w;
                wv[4] = wb.x; wv[5] = wb.y; wv[6] = wb.z; wv[7] = wb.w;
            } else if (l15 < 4) {
                const float* wr = ((l15 < 2) ? (Wqxy + (l15 << 6))
                                             : (Wkxy + ((l15 - 2) << 6)))
                                  + (ks << 5) + (g << 3);
                float4 wa = *(const float4*)wr, wb = *(const float4*)(wr + 4);
                wv[0] = wa.x; wv[1] = wa.y; wv[2] = wa.z; wv[3] = wa.w;
                wv[4] = wb.x; wv[5] = wb.y; wv[6] = wb.z; wv[7] = wb.w;
            }
            bf16x8 wh, wl;
            #pragma unroll
            for (int i = 0; i < 8; i++) {
                u32 hb = f2bf(wv[i]);
                float rr = wv[i] - __uint_as_float(hb << 16);
                wh[i] = (short)hb;
                wl[i] = (short)f2bf(rr);
            }
            acc = __builtin_amdgcn_mfma_f32_16x16x32_bf16(ah[ks], wh, acc, 0, 0, 0);
            acc = __builtin_amdgcn_mfma_f32_16x16x32_bf16(al[ks], wh, acc, 0, 0, 0);
            acc = __builtin_amdgcn_mfma_f32_16x16x32_bf16(ah[ks], wl, acc, 0, 0, 0);
        }
        if (jt < 2) {
            #pragma unroll
            for (int r = 0; r < 4; r++)
                QT[(((b << 10) + n0 + (g << 2) + r) << 5) + (jt << 4) + l15]
                    = (u16)f2bf(acc[r]);
        } else if (jt < 4) {
            #pragma unroll
            for (int r = 0; r < 4; r++)
                KT[(((b << 10) + n0 + (g << 2) + r) << 5) + ((jt - 2) << 4) + l15]
                    = (u16)f2bf(acc[r]);
        } else if (jt < 6) {
            int kd = ((jt - 4) << 4) + l15;
            uint2 d = make_uint2(pk2(acc[0], acc[1]), pk2(acc[2], acc[3]));
            *(uint2*)&VW[((b << 5) + kd) * VWS + n0 + (g << 2)] = d;
        } else {
            if (l15 < 2) {
                #pragma unroll
                for (int r = 0; r < 4; r++)
                    QXY[(((b << 10) + n0 + (g << 2) + r) << 1) + l15] = acc[r];
            } else if (l15 < 4) {
                #pragma unroll
                for (int r = 0; r < 4; r++)
                    KXY[(((b << 10) + n0 + (g << 2) + r) << 1) + (l15 - 2)] = acc[r];
            }
        }
    }

    if ((bid & 63) == 63 && l < 32)
        *(uint4*)&VW[((b << 5) + l) * VWS + 1024] = make_uint4(0, 0, 0, 0);
}

// ---------- attention: 512 blocks = (b, 8x4-query tile); 4 waves x 8 queries ----
// Swapped QK^T: acc = mfma(K, Q) -> lane (g,lq) holds S[slot=(t,4g+r)][q=lq].
// Softmax: per-lane partial max/sum over its 80 slots, then cross-g combine
// via 2+2 shfl_xor (lanes lq/lq+16/lq+32/lq+48 hold the same query's row).
// PV k-blocks = tile pairs -> A-frag is the lane's own acc (no transpose).
// xy-scores folded in as a hi/lo-split MFMA (fp32-equivalent precision).
// 2 barriers, no LDS exchange, 50KB LDS -> 3 blocks/CU.
__global__ __launch_bounds__(256, 3) void attn_kernel(
    const char* __restrict__ wsb, const float* __restrict__ Wout,
    float* __restrict__ out)
{
    const u16* QT = (const u16*)(wsb + WS_QT);
    const u16* KT = (const u16*)(wsb + WS_KT);
    const u16* VW = (const u16*)(wsb + WS_VW);
    const float* QXY = (const float*)(wsb + WS_QXY);
    const float* KXY = (const float*)(wsb + WS_KXY);

    __shared__ __align__(16) u16 kfr[20 * 64 * 8];    // [t][g][sc][8ch] 20.5KB
    __shared__ __align__(16) u16 vfr[10 * 128 * 8];   // [kk][g][kd][8j] 20.5KB
    __shared__ __align__(16) u32 kxyb[320 * 2];       // hi/lo packed  2.5KB
    __shared__ __align__(16) u16 wfr[4 * 64 * 8];     // Wout^T frags  4KB
    __shared__ __align__(16) u16 o_l[4 * 8 * 32];     // O transpose   2KB

    int tid = threadIdx.x, bid = blockIdx.x;
    int b = bid >> 5, t5 = bid & 31;
    int qy0 = (t5 >> 3) << 3, qx0 = (t5 & 7) << 2;
    int ry0 = qy0 - 6, rx0 = qx0 - 6;

    // ---- stage K fragments: chunk c -> (t=c>>6, chgrp=(c>>4)&3, sc=c&15)
    #pragma unroll
    for (int i = 0; i < 5; i++) {
        int c = tid + (i << 8);
        int t = c >> 6, g2 = (c >> 4) & 3, sc = c & 15;
        int n2 = (ry0 + t) * 32 + rx0 + sc;
        n2 = max(0, min(1023, n2));
        uint4 d = *(const uint4*)(KT + (((b << 10) + n2) << 5) + (g2 << 3));
        *(uint4*)&kfr[c << 3] = d;
    }
    // ---- stage V fragments: granule d -> (p=d&1, kd=(d>>1)&31, g=(d>>6)&3, kk=d>>8)
    // granule = 4 u16 (j = 4p..4p+3) = V[slots rr=2kk+p, cols 4g..4g+3][kd]
    #pragma unroll
    for (int i = 0; i < 10; i++) {
        int d = tid + (i << 8);
        int p = d & 1, kd = (d >> 1) & 31, g2 = (d >> 6) & 3, kk = d >> 8;
        int ky = ry0 + (kk << 1) + p;
        int n = ky * 32 + rx0 + (g2 << 2);
        if ((u32)ky > 31u) n = 0;               // masked rows -> finite data
        const u32* s = (const u32*)(VW + ((b << 5) + kd) * VWS + n);
        *(uint2*)&vfr[d << 2] = make_uint2(s[0], s[1]);
    }
    // ---- stage kxy hi/lo packed per slot
    for (int i = tid; i < 320; i += 256) {
        int n2 = (ry0 + (i >> 4)) * 32 + rx0 + (i & 15);
        n2 = max(0, min(1023, n2));
        float2 f = *(const float2*)(KXY + (((b << 10) + n2) << 1));
        u32 h0 = f2bf(f.x), h1 = f2bf(f.y);
        float r0 = f.x - __uint_as_float(h0 << 16);
        float r1 = f.y - __uint_as_float(h1 << 16);
        kxyb[(i << 1)]     = h0 | (h1 << 16);
        kxyb[(i << 1) + 1] = f2bf(r0) | (f2bf(r1) << 16);
    }
    // ---- stage Wout^T fragments
    {
        int nt = tid >> 6, l = tid & 63;
        int cc = (nt << 4) + (l & 15);
        const float* wsrc = Wout + (cc << 5) + ((l >> 4) << 3);
        uint4 dw;
        dw.x = pk2(wsrc[0], wsrc[1]); dw.y = pk2(wsrc[2], wsrc[3]);
        dw.z = pk2(wsrc[4], wsrc[5]); dw.w = pk2(wsrc[6], wsrc[7]);
        *(uint4*)&wfr[tid << 3] = dw;
    }

    // ---- per-lane query setup (loads issued pre-barrier)
    int w = tid >> 6, ll = tid & 63;
    int lq = ll & 15, g = ll >> 4;
    int qloc = lq & 7;                         // cols 8-15 duplicate 0-7
    int qrow = (w << 1) + (qloc >> 2), qcol = qloc & 3;
    int nq = (qy0 + qrow) * 32 + qx0 + qcol;
    uint4 bqu = *(const uint4*)(QT + (((b << 10) + nq) << 5) + (g << 3));
    float2 qv = *(const float2*)(QXY + (((b << 10) + nq) << 1));
    u32 qh0 = f2bf(qv.x), qh1 = f2bf(qv.y);
    float qr0 = qv.x - __uint_as_float(qh0 << 16);
    float qr1 = qv.y - __uint_as_float(qh1 << 16);
    u32 qhp = qh0 | (qh1 << 16);
    u32 qlp = f2bf(qr0) | (f2bf(qr1) << 16);
    uint4 bxyu = make_uint4(g == 0 ? qhp : 0, g == 0 ? qlp : 0,
                            g == 0 ? qhp : 0, 0);

    __syncthreads();

    // ---- QK^T (swapped) + xy-score MFMA: acc[t][r] = S[slot=t*16+4g+r][q=lq]
    f32x4 acc[20];
    #pragma unroll
    for (int t = 0; t < 20; t++) {
        uint2 kp = *(const uint2*)&kxyb[((t << 4) + lq) << 1];
        U4H axy; axy.u = make_uint4(g == 0 ? kp.x : 0, g == 0 ? kp.x : 0,
                                    g == 0 ? kp.y : 0, 0);
        U4H bxy; bxy.u = bxyu;
        f32x4 z = {0.f, 0.f, 0.f, 0.f};
        f32x4 a0 = __builtin_amdgcn_mfma_f32_16x16x32_bf16(axy.h, bxy.h, z, 0, 0, 0);
        U4H ak; ak.u = *(const uint4*)&kfr[((t << 6) + (g << 4) + lq) << 3];
        U4H bq; bq.u = bqu;
        acc[t] = __builtin_amdgcn_mfma_f32_16x16x32_bf16(ak.h, bq.h, a0, 0, 0, 0);
    }

    // ---- mask + softmax: per-lane partials + cross-g combine (4 shuffles)
    int dx2a[4], kxa[4];
    #pragma unroll
    for (int r = 0; r < 4; r++) {
        int sc = (g << 2) + r;
        int kx = rx0 + sc;
        kxa[r] = (kx >= 0) && (kx < 32);
        int dx = sc - 6 - qcol;
        dx2a[r] = dx * dx;
    }
    float m = -1e30f;
    #pragma unroll
    for (int t = 0; t < 20; t++) {
        int ky = ry0 + t;
        bool kyok = (ky >= 0) && (ky < 32);
        int dy = t - 6 - qrow, dy2 = dy * dy;
        #pragma unroll
        for (int r = 0; r < 4; r++) {
            bool ok = kyok && kxa[r] && (dy2 + dx2a[r] <= 36);
            acc[t][r] = ok ? acc[t][r] : -1e4f;
            m = fmaxf(m, acc[t][r]);
        }
    }
    // combine the 4 column-stripes of this query's row (lanes lq+16g')
    m = fmaxf(m, __shfl_xor(m, 16, 64));
    m = fmaxf(m, __shfl_xor(m, 32, 64));

    float sum = 0.f;
    #pragma unroll
    for (int t = 0; t < 20; t++) {
        #pragma unroll
        for (int r = 0; r < 4; r++) {
            float e = __expf(acc[t][r] - m);
            acc[t][r] = e;
            sum += e;
        }
    }
    sum += __shfl_xor(sum, 16, 64);
    sum += __shfl_xor(sum, 32, 64);

    float rinv = 1.f / sum;
    #pragma unroll
    for (int t = 0; t < 20; t++) {
        #pragma unroll
        for (int r = 0; r < 4; r++) acc[t][r] *= rinv;   // pre-scale P (linear)
    }

    // ---- PV: k-block kk = tiles (2kk, 2kk+1) -> A-frag is lane-local acc
    f32x4 o0 = {0.f, 0.f, 0.f, 0.f}, o1 = {0.f, 0.f, 0.f, 0.f};
    #pragma unroll
    for (int kk = 0; kk < 10; kk++) {
        U4H pa;
        pa.u = make_uint4(pk2(acc[2 * kk][0],     acc[2 * kk][1]),
                          pk2(acc[2 * kk][2],     acc[2 * kk][3]),
                          pk2(acc[2 * kk + 1][0], acc[2 * kk + 1][1]),
                          pk2(acc[2 * kk + 1][2], acc[2 * kk + 1][3]));
        U4H v0; v0.u = *(const uint4*)&vfr[((kk << 7) + (g << 5) + lq) << 3];
        U4H v1; v1.u = *(const uint4*)&vfr[((kk << 7) + (g << 5) + lq + 16) << 3];
        o0 = __builtin_amdgcn_mfma_f32_16x16x32_bf16(pa.h, v0.h, o0, 0, 0, 0);
        o1 = __builtin_amdgcn_mfma_f32_16x16x32_bf16(pa.h, v1.h, o1, 0, 0, 0);
    }

    // ---- O transpose via tiny per-wave LDS (rows q<8 real; 8-15 were dups)
    if (g < 2) {
        #pragma unroll
        for (int r = 0; r < 4; r++) {
            int q = (g << 2) + r;
            o_l[(w << 8) + (q << 5) + lq]      = (u16)f2bf(o0[r]);
            o_l[(w << 8) + (q << 5) + lq + 16] = (u16)f2bf(o1[r]);
        }
    }
    __syncthreads();

    // ---- epilogue: Y = O * Wout^T, 4 column tiles
    U4H aO; aO.u = *(const uint4*)&o_l[(w << 8) + (qloc << 5) + (g << 3)];
    int nqb = (qy0 + (w << 1) + g) * 32 + qx0;   // row for q = g*4+r (g<2)
    #pragma unroll
    for (int nt2 = 0; nt2 < 4; nt2++) {
        U4H bw; bw.u = *(const uint4*)&wfr[((nt2 << 6) + ll) << 3];
        f32x4 z = {0.f, 0.f, 0.f, 0.f};
        f32x4 y = __builtin_amdgcn_mfma_f32_16x16x32_bf16(aO.h, bw.h, z, 0, 0, 0);
        if (g < 2) {
            int cc = (nt2 << 4) + lq;
            #pragma unroll
            for (int r = 0; r < 4; r++)
                out[(((b << 6) + cc) << 10) + nqb + r] = y[r];
        }
    }
}

extern "C" void kernel_launch(void* const* d_in, const int* in_sizes, int n_in,
                              void* d_out, int out_size, void* d_ws, size_t ws_size,
                              hipStream_t stream) {
    const float* x    = (const float*)d_in[0];
    const float* Wq   = (const float*)d_in[1];
    const float* Wk   = (const float*)d_in[2];
    const float* Wv   = (const float*)d_in[3];
    const float* Wqxy = (const float*)d_in[4];
    const float* Wkxy = (const float*)d_in[5];
    const float* Wout = (const float*)d_in[6];
    float* out = (float*)d_out;
    char* wsb  = (char*)d_ws;

    proj_kernel<<<1024, 64, 0, stream>>>(x, Wq, Wk, Wv, Wqxy, Wkxy, wsb);
    attn_kernel<<<512, 256, 0, stream>>>(wsb, Wout, out);
}